// Round 4
// baseline (310.297 us; speedup 1.0000x reference)
//
#include <hip/hip_runtime.h>
#include <hip/hip_bf16.h>

#define N_NODES 100000
#define N_EDGES 1600000
#define IN_DIM 128
#define HID 64
#define NB ((N_NODES + 255) / 256)   // 391 buckets of 256 dst nodes
#define NSUB 8                       // sub-slots per bucket (contention spread)
#define SUBCAP 1024                  // capacity per sub-slot (max fill ~620)
#define MAXPB (NSUB * SUBCAP)        // 8192 records per bucket region

typedef __attribute__((ext_vector_type(8))) short bf16x8;
typedef __attribute__((ext_vector_type(4))) float f32x4;

// ---------------- threefry2x32, key = (0, 42) ----------------
__device__ __forceinline__ unsigned rotl32(unsigned x, unsigned r) {
    return (x << r) | (x >> (32u - r));
}

__device__ __forceinline__ void threefry2x32_k42(unsigned x0, unsigned x1,
                                                 unsigned& o0, unsigned& o1) {
    const unsigned ks0 = 0u;
    const unsigned ks1 = 42u;
    const unsigned ks2 = 0u ^ 42u ^ 0x1BD11BDAu;
    x0 += ks0; x1 += ks1;
    x0 += x1; x1 = rotl32(x1, 13); x1 ^= x0;
    x0 += x1; x1 = rotl32(x1, 15); x1 ^= x0;
    x0 += x1; x1 = rotl32(x1, 26); x1 ^= x0;
    x0 += x1; x1 = rotl32(x1, 6);  x1 ^= x0;
    x0 += ks1; x1 += ks2 + 1u;
    x0 += x1; x1 = rotl32(x1, 17); x1 ^= x0;
    x0 += x1; x1 = rotl32(x1, 29); x1 ^= x0;
    x0 += x1; x1 = rotl32(x1, 16); x1 ^= x0;
    x0 += x1; x1 = rotl32(x1, 24); x1 ^= x0;
    x0 += ks2; x1 += ks0 + 2u;
    x0 += x1; x1 = rotl32(x1, 13); x1 ^= x0;
    x0 += x1; x1 = rotl32(x1, 15); x1 ^= x0;
    x0 += x1; x1 = rotl32(x1, 26); x1 ^= x0;
    x0 += x1; x1 = rotl32(x1, 6);  x1 ^= x0;
    x0 += ks0; x1 += ks1 + 3u;
    x0 += x1; x1 = rotl32(x1, 17); x1 ^= x0;
    x0 += x1; x1 = rotl32(x1, 29); x1 ^= x0;
    x0 += x1; x1 = rotl32(x1, 16); x1 ^= x0;
    x0 += x1; x1 = rotl32(x1, 24); x1 ^= x0;
    x0 += ks1; x1 += ks2 + 4u;
    x0 += x1; x1 = rotl32(x1, 13); x1 ^= x0;
    x0 += x1; x1 = rotl32(x1, 15); x1 ^= x0;
    x0 += x1; x1 = rotl32(x1, 26); x1 ^= x0;
    x0 += x1; x1 = rotl32(x1, 6);  x1 ^= x0;
    x0 += ks2; x1 += ks0 + 5u;
    o0 = x0; o1 = x1;
}

__device__ __forceinline__ float bf2f(unsigned short u) {
    return __uint_as_float((unsigned)u << 16);
}
// low/high bf16 of a packed uint
__device__ __forceinline__ float bf2f_lo(unsigned u) {
    return __uint_as_float(u << 16);
}
__device__ __forceinline__ float bf2f_hi(unsigned u) {
    return __uint_as_float(u & 0xffff0000u);
}

// ---- phase 1: direct bucketed scatter via global sub-cursors ----
// record = (c & 255) << 17 | r   (r < 2^17). Sub-slot = e & 7 spreads the
// atomic contention over NB*NSUB = 3128 cursors (~512 RMWs each).
__global__ __launch_bounds__(256) void k_bucket2(const int* __restrict__ src,
                                                 const int* __restrict__ dst,
                                                 int* __restrict__ subcnt,
                                                 unsigned* __restrict__ gbuf) {
    const int gid = blockIdx.x * 256 + threadIdx.x;
    const int e0 = gid * 4;
    if (e0 >= N_EDGES) return;
    const int4 s4 = *(const int4*)(src + e0);
    const int4 d4 = *(const int4*)(dst + e0);
    const int ss[4] = {s4.x, s4.y, s4.z, s4.w};
    const int dd[4] = {d4.x, d4.y, d4.z, d4.w};
#pragma unroll
    for (int k = 0; k < 4; k++) {
        const int b = dd[k] >> 8;
        const int sub = (e0 + k) & (NSUB - 1);
        const unsigned rec = ((unsigned)(dd[k] & 255) << 17) | (unsigned)ss[k];
        const int p = atomicAdd(&subcnt[b * NSUB + sub], 1);
        gbuf[(size_t)b * MAXPB + sub * SUBCAP + p] = rec;
    }
}

// ---- phase 2: per-bucket count + scan + row_se + dinv + in-place place ----
// Reads the bucket's 8 sub-segments into LDS, counts per-dst degrees, local
// scan, then scatters srcs IN PLACE over the same gbuf region (fixed base
// b*MAXPB — no global scan / bucket_base needed).
__global__ __launch_bounds__(256) void k_csr3(unsigned* __restrict__ gbuf,
                                              const int* __restrict__ subcnt,
                                              int2* __restrict__ row_se,
                                              float* __restrict__ dinv) {
    __shared__ unsigned lbuf[MAXPB];  // 32 KB
    __shared__ int lcnt[256];
    __shared__ int pre[256];
    __shared__ int cur[256];
    __shared__ int c8[NSUB + 1];
    const int b = blockIdx.x, t = threadIdx.x;
    if (t == 0) {
        int acc = 0;
        for (int s = 0; s < NSUB; s++) { c8[s] = acc; acc += subcnt[b * NSUB + s]; }
        c8[NSUB] = acc;
    }
    lcnt[t] = 0;
    __syncthreads();
    // compact the 8 sub-segments into contiguous lbuf[0..n)
    for (int s = 0; s < NSUB; s++) {
        const int n_s = c8[s + 1] - c8[s];
        const unsigned* seg = gbuf + (size_t)b * MAXPB + s * SUBCAP;
        for (int j = t; j < n_s; j += 256) lbuf[c8[s] + j] = seg[j];
    }
    const int n = c8[NSUB];
    __syncthreads();
    for (int j = t; j < n; j += 256) atomicAdd(&lcnt[lbuf[j] >> 17], 1);
    __syncthreads();
    const int my = lcnt[t];
    pre[t] = my;
    __syncthreads();
    for (int o = 1; o < 256; o <<= 1) {
        int v = (t >= o) ? pre[t - o] : 0;
        __syncthreads();
        pre[t] += v;
        __syncthreads();
    }
    const int base = b * MAXPB + pre[t] - my;  // absolute pos in gbuf region
    cur[t] = base;
    const int c = b * 256 + t;
    if (c < N_NODES) {
        row_se[c] = make_int2(base, base + my);
        dinv[c] = rsqrtf((float)(my + 1));  // in-degree + self-loop
    }
    __syncthreads();
    // in-place: all records are safe in lbuf; overwrite region with src ids
    for (int j = t; j < n; j += 256) {
        const unsigned rec = lbuf[j];
        const int pos = atomicAdd(&cur[rec >> 17], 1);
        ((int*)gbuf)[pos] = (int)(rec & 0x1FFFF);
    }
}

// ------ g = (x @ W_conv) * dinv[row], bf16 out — MFMA split-bf16 version ------
// 3-pass split: x=xh+xl, W=Wh+Wl (bf16 each); h = xh@Wh + xl@Wh + xh@Wl.
__global__ __launch_bounds__(256) void k_gemm(const float* __restrict__ x,
                                              const float* __restrict__ W,
                                              const float* __restrict__ dinv,
                                              unsigned short* __restrict__ gm) {
    __shared__ unsigned short WtH[HID][136];
    __shared__ unsigned short WtL[HID][136];
    const int t = threadIdx.x;
    {
        const int n = t & 63;
        const int k0 = (t >> 6) * 32;
        for (int k = k0; k < k0 + 32; k += 2) {
            float w0 = W[(size_t)k * HID + n];
            float w1 = W[(size_t)(k + 1) * HID + n];
            unsigned short h0 = __bfloat16_as_ushort(__float2bfloat16(w0));
            unsigned short h1 = __bfloat16_as_ushort(__float2bfloat16(w1));
            unsigned short l0 = __bfloat16_as_ushort(__float2bfloat16(w0 - bf2f(h0)));
            unsigned short l1 = __bfloat16_as_ushort(__float2bfloat16(w1 - bf2f(h1)));
            *(unsigned*)&WtH[n][k] = (unsigned)h0 | ((unsigned)h1 << 16);
            *(unsigned*)&WtL[n][k] = (unsigned)l0 | ((unsigned)l1 << 16);
        }
    }
    __syncthreads();

    const int wave = t >> 6, lane = t & 63;
    const int row16 = lane & 15;   // A-frag row within tile / B-frag col
    const int kgrp = lane >> 4;    // k-subgroup
    const int browA = blockIdx.x * 64 + wave * 16;

    const int rA = min(browA + row16, N_NODES - 1);  // clamp tail reads
    const float* xr = x + (size_t)rA * IN_DIM + kgrp * 8;
    float xv[32];
#pragma unroll
    for (int ks = 0; ks < 4; ks++) {
        *(f32x4*)&xv[ks * 8]     = *(const f32x4*)(xr + ks * 32);
        *(f32x4*)&xv[ks * 8 + 4] = *(const f32x4*)(xr + ks * 32 + 4);
    }
    bf16x8 ah[4], al[4];
#pragma unroll
    for (int ks = 0; ks < 4; ks++) {
#pragma unroll
        for (int j = 0; j < 8; j++) {
            float v = xv[ks * 8 + j];
            unsigned short h = __bfloat16_as_ushort(__float2bfloat16(v));
            unsigned short l = __bfloat16_as_ushort(__float2bfloat16(v - bf2f(h)));
            ah[ks][j] = (short)h;
            al[ks][j] = (short)l;
        }
    }

    float dv[4];
    int orow[4];
#pragma unroll
    for (int i = 0; i < 4; i++) {
        orow[i] = browA + kgrp * 4 + i;
        dv[i] = dinv[min(orow[i], N_NODES - 1)];
    }

#pragma unroll
    for (int nt = 0; nt < 4; nt++) {
        const int n = nt * 16 + row16;
        bf16x8 bh[4], bl[4];
#pragma unroll
        for (int ks = 0; ks < 4; ks++) {
            bh[ks] = *(const bf16x8*)&WtH[n][ks * 32 + kgrp * 8];
            bl[ks] = *(const bf16x8*)&WtL[n][ks * 32 + kgrp * 8];
        }
        f32x4 acc = {0.f, 0.f, 0.f, 0.f};
#pragma unroll
        for (int ks = 0; ks < 4; ks++)
            acc = __builtin_amdgcn_mfma_f32_16x16x32_bf16(ah[ks], bh[ks], acc, 0, 0, 0);
#pragma unroll
        for (int ks = 0; ks < 4; ks++)
            acc = __builtin_amdgcn_mfma_f32_16x16x32_bf16(al[ks], bh[ks], acc, 0, 0, 0);
#pragma unroll
        for (int ks = 0; ks < 4; ks++)
            acc = __builtin_amdgcn_mfma_f32_16x16x32_bf16(ah[ks], bl[ks], acc, 0, 0, 0);
#pragma unroll
        for (int i = 0; i < 4; i++) {
            if (orow[i] < N_NODES) {
                float g = acc[i] * dv[i];
                gm[(size_t)orow[i] * HID + nt * 16 + row16] =
                    __bfloat16_as_ushort(__float2bfloat16(g));
            }
        }
    }
}

// ------- fused gather(bf16 g) + self + bias/relu/dropout + [64->2] matvec -------
// 16 lanes per dst (4 dims/lane, dwordx2), 4 dsts/wave. ALL edges processed in
// masked 8-batches, two buffers ping-pong. Extent from row_se[c] (int2).
__global__ __launch_bounds__(256, 4) void k_aggr(const unsigned short* __restrict__ gm,
                                                 const int2* __restrict__ row_se,
                                                 const int* __restrict__ srcs,
                                                 const float* __restrict__ dinv,
                                                 const float* __restrict__ bconv,
                                                 const float* __restrict__ Wlin,
                                                 const float* __restrict__ blin,
                                                 float* __restrict__ out) {
    const int c  = blockIdx.x * 16 + (threadIdx.x >> 4);  // dst node, group of 16 lanes
    const int d4 = threadIdx.x & 15;                      // dim quad: dims [4*d4, 4*d4+4)
    const int2 se = row_se[c];
    const int beg = se.x;
    const int end = se.y;

    // self-loop term g[c] (accumulation order: self first, then j asc)
    const uint2 s0 = *(const uint2*)(gm + ((size_t)c << 6) + (d4 << 2));
    float a0 = bf2f_lo(s0.x), a1 = bf2f_hi(s0.x);
    float a2 = bf2f_lo(s0.y), a3 = bf2f_hi(s0.y);

#define LOADG(ri) (*(const uint2*)(gm + ((size_t)(ri) << 6) + (d4 << 2)))

    if (beg < end) {
        const int last = end - 1;
        int r[8];
        uint2 wa[8], wb[8];
        // batch 0 -> wa
#pragma unroll
        for (int u = 0; u < 8; u++) r[u] = srcs[min(beg + u, last)];
#pragma unroll
        for (int u = 0; u < 8; u++) wa[u] = LOADG(r[u]);
        bool haveB = (beg + 8 < end);
        if (haveB) {
#pragma unroll
            for (int u = 0; u < 8; u++) r[u] = srcs[min(beg + 8 + u, last)];
#pragma unroll
            for (int u = 0; u < 8; u++) wb[u] = LOADG(r[u]);
        }
        int j = beg;
        while (true) {
            // accumulate wa for [j, j+8), masked (masked adds contribute exact 0.0f)
#pragma unroll
            for (int u = 0; u < 8; u++) {
                const unsigned m = (j + u < end) ? 0xffffffffu : 0u;
                a0 += bf2f_lo(wa[u].x & m); a1 += bf2f_hi(wa[u].x & m);
                a2 += bf2f_lo(wa[u].y & m); a3 += bf2f_hi(wa[u].y & m);
            }
            j += 8;
            if (!haveB) break;
            // prefetch batch after wb into wa (issues before wb's accumulate)
            const bool haveN = (j + 8 < end);
            if (haveN) {
#pragma unroll
                for (int u = 0; u < 8; u++) r[u] = srcs[min(j + 8 + u, last)];
#pragma unroll
                for (int u = 0; u < 8; u++) wa[u] = LOADG(r[u]);
            }
            // accumulate wb for [j, j+8)
#pragma unroll
            for (int u = 0; u < 8; u++) {
                const unsigned m = (j + u < end) ? 0xffffffffu : 0u;
                a0 += bf2f_lo(wb[u].x & m); a1 += bf2f_hi(wb[u].x & m);
                a2 += bf2f_lo(wb[u].y & m); a3 += bf2f_hi(wb[u].y & m);
            }
            j += 8;
            if (!haveN) break;
            haveB = (j + 8 < end);
            if (haveB) {
#pragma unroll
                for (int u = 0; u < 8; u++) r[u] = srcs[min(j + 8 + u, last)];
#pragma unroll
                for (int u = 0; u < 8; u++) wb[u] = LOADG(r[u]);
            }
        }
    }
#undef LOADG

    const float dv = dinv[c];
    const float4 bc4 = *(const float4*)(bconv + (d4 << 2));
    float v0 = fmaxf(a0 * dv + bc4.x, 0.f);
    float v1 = fmaxf(a1 * dv + bc4.y, 0.f);
    float v2 = fmaxf(a2 * dv + bc4.z, 0.f);
    float v3 = fmaxf(a3 * dv + bc4.w, 0.f);

    // dropout: per-element threefry mapping i = c*64 + d
    const unsigned ib = (unsigned)(c * HID + (d4 << 2));
    unsigned o0, o1;
    threefry2x32_k42(0u, ib + 0u, o0, o1);
    v0 = ((o0 ^ o1) & 0x80000000u) ? 0.f : v0 * 2.f;
    threefry2x32_k42(0u, ib + 1u, o0, o1);
    v1 = ((o0 ^ o1) & 0x80000000u) ? 0.f : v1 * 2.f;
    threefry2x32_k42(0u, ib + 2u, o0, o1);
    v2 = ((o0 ^ o1) & 0x80000000u) ? 0.f : v2 * 2.f;
    threefry2x32_k42(0u, ib + 3u, o0, o1);
    v3 = ((o0 ^ o1) & 0x80000000u) ? 0.f : v3 * 2.f;

    // [64 -> 2] matvec partials: Wlin row-major [64][2]; lane covers rows 4*d4..4*d4+3
    const float4 wl0 = *(const float4*)(Wlin + (d4 << 3));      // rows 4d4, 4d4+1
    const float4 wl1 = *(const float4*)(Wlin + (d4 << 3) + 4);  // rows 4d4+2, 4d4+3
    float p0 = v0 * wl0.x + v1 * wl0.z + v2 * wl1.x + v3 * wl1.z;
    float p1 = v0 * wl0.y + v1 * wl0.w + v2 * wl1.y + v3 * wl1.w;

    // reduce across the 16 lanes of this dst group (aligned, so xor stays in-group)
#pragma unroll
    for (int off = 8; off; off >>= 1) {
        p0 += __shfl_xor(p0, off);
        p1 += __shfl_xor(p1, off);
    }
    if (d4 == 0) {
        *(float2*)(out + (size_t)c * 2) = make_float2(p0 + blin[0], p1 + blin[1]);
    }
}

extern "C" void kernel_launch(void* const* d_in, const int* in_sizes, int n_in,
                              void* d_out, int out_size, void* d_ws, size_t ws_size,
                              hipStream_t stream) {
    // Map inputs BY ELEMENT COUNT (all unique) — robust to positional order.
    const float* x  = (const float*)d_in[0];
    const void*  ei = d_in[1];
    const float* Wc = (const float*)d_in[2];
    const float* bc = (const float*)d_in[3];
    const float* Wl = (const float*)d_in[4];
    const float* bl = (const float*)d_in[5];
    for (int i = 0; i < n_in; i++) {
        switch (in_sizes[i]) {
            case N_NODES * IN_DIM:   x  = (const float*)d_in[i]; break;
            case 2 * N_EDGES:
            case 4 * N_EDGES:        ei = d_in[i]; break;
            case IN_DIM * HID:       Wc = (const float*)d_in[i]; break;
            case HID:                bc = (const float*)d_in[i]; break;
            case HID * 2:            Wl = (const float*)d_in[i]; break;
            case 2:                  bl = (const float*)d_in[i]; break;
            default: break;
        }
    }
    float* out = (float*)d_out;

    const int* src = (const int*)ei;            // edge_index[0] (int32, proven r2≡r3)
    const int* dst = (const int*)ei + N_EDGES;  // edge_index[1]

    char* ws = (char*)d_ws;
    size_t off = 0;
    unsigned short* gm = (unsigned short*)(ws + off); off += (size_t)N_NODES * HID * 2;  // 12.8 MB
    float* dinv        = (float*)(ws + off);   off += (size_t)N_NODES * 4;               // 0.4 MB
    int2*  row_se      = (int2*)(ws + off);    off += (size_t)N_NODES * 8;               // 0.8 MB
    int*   subcnt      = (int*)(ws + off);     off += (size_t)(NB * NSUB + 64) * 4;      // 12.5 KB
    off = (off + 255) & ~(size_t)255;
    unsigned* gbuf     = (unsigned*)(ws + off); off += (size_t)NB * MAXPB * 4;           // 12.8 MB
    // gbuf doubles as srcs (records overwritten in place by k_csr3)

    hipMemsetAsync(subcnt, 0, (size_t)NB * NSUB * 4, stream);
    k_bucket2<<<(N_EDGES / 4 + 255) / 256, 256, 0, stream>>>(src, dst, subcnt, gbuf);
    k_csr3<<<NB, 256, 0, stream>>>(gbuf, subcnt, row_se, dinv);
    k_gemm<<<(N_NODES + 63) / 64, 256, 0, stream>>>(x, Wc, dinv, gm);
    k_aggr<<<(N_NODES + 15) / 16, 256, 0, stream>>>(gm, row_se, (const int*)gbuf,
                                                    dinv, bc, Wl, bl, out);
}

// Round 5
// 174.471 us; speedup vs baseline: 1.7785x; 1.7785x over previous
//
#include <hip/hip_runtime.h>
#include <hip/hip_bf16.h>

#define N_NODES 100000
#define N_EDGES 1600000
#define IN_DIM 128
#define HID 64
#define NB ((N_NODES + 255) / 256)          // 391 buckets of 256 dst nodes
#define EPB 4096                            // edges per k_bucket block
#define BUCKET_BLOCKS ((N_EDGES + EPB - 1) / EPB)  // 391
#define MAXPB 8192                          // fixed gbuf region per bucket (mean 4092)

typedef __attribute__((ext_vector_type(8))) short bf16x8;
typedef __attribute__((ext_vector_type(4))) float f32x4;

// ---------------- threefry2x32, key = (0, 42) ----------------
__device__ __forceinline__ unsigned rotl32(unsigned x, unsigned r) {
    return (x << r) | (x >> (32u - r));
}

__device__ __forceinline__ void threefry2x32_k42(unsigned x0, unsigned x1,
                                                 unsigned& o0, unsigned& o1) {
    const unsigned ks0 = 0u;
    const unsigned ks1 = 42u;
    const unsigned ks2 = 0u ^ 42u ^ 0x1BD11BDAu;
    x0 += ks0; x1 += ks1;
    x0 += x1; x1 = rotl32(x1, 13); x1 ^= x0;
    x0 += x1; x1 = rotl32(x1, 15); x1 ^= x0;
    x0 += x1; x1 = rotl32(x1, 26); x1 ^= x0;
    x0 += x1; x1 = rotl32(x1, 6);  x1 ^= x0;
    x0 += ks1; x1 += ks2 + 1u;
    x0 += x1; x1 = rotl32(x1, 17); x1 ^= x0;
    x0 += x1; x1 = rotl32(x1, 29); x1 ^= x0;
    x0 += x1; x1 = rotl32(x1, 16); x1 ^= x0;
    x0 += x1; x1 = rotl32(x1, 24); x1 ^= x0;
    x0 += ks2; x1 += ks0 + 2u;
    x0 += x1; x1 = rotl32(x1, 13); x1 ^= x0;
    x0 += x1; x1 = rotl32(x1, 15); x1 ^= x0;
    x0 += x1; x1 = rotl32(x1, 26); x1 ^= x0;
    x0 += x1; x1 = rotl32(x1, 6);  x1 ^= x0;
    x0 += ks0; x1 += ks1 + 3u;
    x0 += x1; x1 = rotl32(x1, 17); x1 ^= x0;
    x0 += x1; x1 = rotl32(x1, 29); x1 ^= x0;
    x0 += x1; x1 = rotl32(x1, 16); x1 ^= x0;
    x0 += x1; x1 = rotl32(x1, 24); x1 ^= x0;
    x0 += ks1; x1 += ks2 + 4u;
    x0 += x1; x1 = rotl32(x1, 13); x1 ^= x0;
    x0 += x1; x1 = rotl32(x1, 15); x1 ^= x0;
    x0 += x1; x1 = rotl32(x1, 26); x1 ^= x0;
    x0 += x1; x1 = rotl32(x1, 6);  x1 ^= x0;
    x0 += ks2; x1 += ks0 + 5u;
    o0 = x0; o1 = x1;
}

__device__ __forceinline__ float bf2f(unsigned short u) {
    return __uint_as_float((unsigned)u << 16);
}
// low/high bf16 of a packed uint
__device__ __forceinline__ float bf2f_lo(unsigned u) {
    return __uint_as_float(u << 16);
}
__device__ __forceinline__ float bf2f_hi(unsigned u) {
    return __uint_as_float(u & 0xffff0000u);
}

// ---- phase 1: bucketed scatter into FIXED regions (r3 version — proven) ----
// record = (c & 255) << 17 | r   (r < 2^17). LDS count+scan+permute makes the
// global write segmented-contiguous per bucket (~1.3x line amplification).
__global__ __launch_bounds__(512) void k_bucket(const int* __restrict__ src,
                                                const int* __restrict__ dst,
                                                int* __restrict__ bucketcnt,
                                                unsigned* __restrict__ gbuf) {
    __shared__ int cnt[512];
    __shared__ int off[512];
    __shared__ int cur[NB];
    __shared__ int gbase[NB];
    __shared__ unsigned buf[EPB];
    __shared__ unsigned short bkt[EPB];
    const int t = threadIdx.x;
    const int e0 = blockIdx.x * EPB;
    const int n = min(EPB, N_EDGES - e0);
    cnt[t] = 0;
    __syncthreads();
    unsigned myrec[EPB / 512];
    int myb[EPB / 512];
#pragma unroll
    for (int k = 0; k < EPB / 512; k++) {
        int e = e0 + k * 512 + t;
        if (e < N_EDGES) {
            int r = src[e];
            int c = dst[e];
            int b = c >> 8;
            myrec[k] = ((unsigned)(c & 255) << 17) | (unsigned)r;
            myb[k] = b;
            atomicAdd(&cnt[b], 1);
        } else {
            myb[k] = -1;
        }
    }
    __syncthreads();
    int own = cnt[t];
    for (int o = 1; o < 512; o <<= 1) {
        int v = (t >= o) ? cnt[t - o] : 0;
        __syncthreads();
        cnt[t] += v;
        __syncthreads();
    }
    off[t] = cnt[t] - own;  // exclusive prefix (records sorted by bucket in buf)
    if (t < NB) {
        cur[t] = off[t];
        gbase[t] = t * MAXPB + (own ? atomicAdd(&bucketcnt[t], own) : 0);
    }
    __syncthreads();
#pragma unroll
    for (int k = 0; k < EPB / 512; k++) {
        if (myb[k] >= 0) {
            int p = atomicAdd(&cur[myb[k]], 1);
            buf[p] = myrec[k];
            bkt[p] = (unsigned short)myb[k];
        }
    }
    __syncthreads();
    for (int j = t; j < n; j += 512) {
        int b = bkt[j];
        gbuf[gbase[b] + (j - off[b])] = buf[j];
    }
}

// ---- phase 2: per-bucket count + scan + row_se + dinv + IN-PLACE place ----
// Records are contiguous [0, n) in the bucket's fixed region. Stage to LDS,
// count per-dst degrees, local scan, then overwrite the region with src ids
// grouped by dst. No global scan, no separate srcs array, no k_scanB.
__global__ __launch_bounds__(256) void k_csr3(unsigned* __restrict__ gbuf,
                                              const int* __restrict__ bucketcnt,
                                              int2* __restrict__ row_se,
                                              float* __restrict__ dinv) {
    __shared__ unsigned lbuf[MAXPB];  // 32 KB
    __shared__ int lcnt[256];
    __shared__ int pre[256];
    __shared__ int cur[256];
    const int b = blockIdx.x, t = threadIdx.x;
    const int n = bucketcnt[b];
    const unsigned* reg = gbuf + (size_t)b * MAXPB;
    lcnt[t] = 0;
    for (int j = t; j < n; j += 256) lbuf[j] = reg[j];
    __syncthreads();
    for (int j = t; j < n; j += 256) atomicAdd(&lcnt[lbuf[j] >> 17], 1);
    __syncthreads();
    const int my = lcnt[t];
    pre[t] = my;
    __syncthreads();
    for (int o = 1; o < 256; o <<= 1) {
        int v = (t >= o) ? pre[t - o] : 0;
        __syncthreads();
        pre[t] += v;
        __syncthreads();
    }
    const int base = b * MAXPB + pre[t] - my;  // absolute pos in gbuf
    cur[t] = base;
    const int c = b * 256 + t;
    if (c < N_NODES) {
        row_se[c] = make_int2(base, base + my);
        dinv[c] = rsqrtf((float)(my + 1));  // in-degree + self-loop
    }
    __syncthreads();
    // all records safe in lbuf; overwrite the region with src ids
    for (int j = t; j < n; j += 256) {
        const unsigned rec = lbuf[j];
        const int pos = atomicAdd(&cur[rec >> 17], 1);
        ((int*)gbuf)[pos] = (int)(rec & 0x1FFFF);
    }
}

// ------ g = (x @ W_conv) * dinv[row], bf16 out — MFMA split-bf16 version ------
// 3-pass split: x=xh+xl, W=Wh+Wl (bf16 each); h = xh@Wh + xl@Wh + xh@Wl.
__global__ __launch_bounds__(256) void k_gemm(const float* __restrict__ x,
                                              const float* __restrict__ W,
                                              const float* __restrict__ dinv,
                                              unsigned short* __restrict__ gm) {
    __shared__ unsigned short WtH[HID][136];
    __shared__ unsigned short WtL[HID][136];
    const int t = threadIdx.x;
    {
        const int n = t & 63;
        const int k0 = (t >> 6) * 32;
        for (int k = k0; k < k0 + 32; k += 2) {
            float w0 = W[(size_t)k * HID + n];
            float w1 = W[(size_t)(k + 1) * HID + n];
            unsigned short h0 = __bfloat16_as_ushort(__float2bfloat16(w0));
            unsigned short h1 = __bfloat16_as_ushort(__float2bfloat16(w1));
            unsigned short l0 = __bfloat16_as_ushort(__float2bfloat16(w0 - bf2f(h0)));
            unsigned short l1 = __bfloat16_as_ushort(__float2bfloat16(w1 - bf2f(h1)));
            *(unsigned*)&WtH[n][k] = (unsigned)h0 | ((unsigned)h1 << 16);
            *(unsigned*)&WtL[n][k] = (unsigned)l0 | ((unsigned)l1 << 16);
        }
    }
    __syncthreads();

    const int wave = t >> 6, lane = t & 63;
    const int row16 = lane & 15;   // A-frag row within tile / B-frag col
    const int kgrp = lane >> 4;    // k-subgroup
    const int browA = blockIdx.x * 64 + wave * 16;

    const int rA = min(browA + row16, N_NODES - 1);  // clamp tail reads
    const float* xr = x + (size_t)rA * IN_DIM + kgrp * 8;
    float xv[32];
#pragma unroll
    for (int ks = 0; ks < 4; ks++) {
        *(f32x4*)&xv[ks * 8]     = *(const f32x4*)(xr + ks * 32);
        *(f32x4*)&xv[ks * 8 + 4] = *(const f32x4*)(xr + ks * 32 + 4);
    }
    bf16x8 ah[4], al[4];
#pragma unroll
    for (int ks = 0; ks < 4; ks++) {
#pragma unroll
        for (int j = 0; j < 8; j++) {
            float v = xv[ks * 8 + j];
            unsigned short h = __bfloat16_as_ushort(__float2bfloat16(v));
            unsigned short l = __bfloat16_as_ushort(__float2bfloat16(v - bf2f(h)));
            ah[ks][j] = (short)h;
            al[ks][j] = (short)l;
        }
    }

    float dv[4];
    int orow[4];
#pragma unroll
    for (int i = 0; i < 4; i++) {
        orow[i] = browA + kgrp * 4 + i;
        dv[i] = dinv[min(orow[i], N_NODES - 1)];
    }

#pragma unroll
    for (int nt = 0; nt < 4; nt++) {
        const int n = nt * 16 + row16;
        bf16x8 bh[4], bl[4];
#pragma unroll
        for (int ks = 0; ks < 4; ks++) {
            bh[ks] = *(const bf16x8*)&WtH[n][ks * 32 + kgrp * 8];
            bl[ks] = *(const bf16x8*)&WtL[n][ks * 32 + kgrp * 8];
        }
        f32x4 acc = {0.f, 0.f, 0.f, 0.f};
#pragma unroll
        for (int ks = 0; ks < 4; ks++)
            acc = __builtin_amdgcn_mfma_f32_16x16x32_bf16(ah[ks], bh[ks], acc, 0, 0, 0);
#pragma unroll
        for (int ks = 0; ks < 4; ks++)
            acc = __builtin_amdgcn_mfma_f32_16x16x32_bf16(al[ks], bh[ks], acc, 0, 0, 0);
#pragma unroll
        for (int ks = 0; ks < 4; ks++)
            acc = __builtin_amdgcn_mfma_f32_16x16x32_bf16(ah[ks], bl[ks], acc, 0, 0, 0);
#pragma unroll
        for (int i = 0; i < 4; i++) {
            if (orow[i] < N_NODES) {
                float g = acc[i] * dv[i];
                gm[(size_t)orow[i] * HID + nt * 16 + row16] =
                    __bfloat16_as_ushort(__float2bfloat16(g));
            }
        }
    }
}

// ------- fused gather(bf16 g) + self + bias/relu/dropout + [64->2] matvec -------
// 16 lanes per dst (4 dims/lane, dwordx2), 4 dsts/wave. ALL edges processed in
// masked 8-batches, two buffers ping-pong. Extent from row_se[c] (int2).
__global__ __launch_bounds__(256, 4) void k_aggr(const unsigned short* __restrict__ gm,
                                                 const int2* __restrict__ row_se,
                                                 const int* __restrict__ srcs,
                                                 const float* __restrict__ dinv,
                                                 const float* __restrict__ bconv,
                                                 const float* __restrict__ Wlin,
                                                 const float* __restrict__ blin,
                                                 float* __restrict__ out) {
    const int c  = blockIdx.x * 16 + (threadIdx.x >> 4);  // dst node, group of 16 lanes
    const int d4 = threadIdx.x & 15;                      // dim quad: dims [4*d4, 4*d4+4)
    const int2 se = row_se[c];
    const int beg = se.x;
    const int end = se.y;

    // self-loop term g[c] (accumulation order: self first, then j asc)
    const uint2 s0 = *(const uint2*)(gm + ((size_t)c << 6) + (d4 << 2));
    float a0 = bf2f_lo(s0.x), a1 = bf2f_hi(s0.x);
    float a2 = bf2f_lo(s0.y), a3 = bf2f_hi(s0.y);

#define LOADG(ri) (*(const uint2*)(gm + ((size_t)(ri) << 6) + (d4 << 2)))

    if (beg < end) {
        const int last = end - 1;
        int r[8];
        uint2 wa[8], wb[8];
        // batch 0 -> wa
#pragma unroll
        for (int u = 0; u < 8; u++) r[u] = srcs[min(beg + u, last)];
#pragma unroll
        for (int u = 0; u < 8; u++) wa[u] = LOADG(r[u]);
        bool haveB = (beg + 8 < end);
        if (haveB) {
#pragma unroll
            for (int u = 0; u < 8; u++) r[u] = srcs[min(beg + 8 + u, last)];
#pragma unroll
            for (int u = 0; u < 8; u++) wb[u] = LOADG(r[u]);
        }
        int j = beg;
        while (true) {
            // accumulate wa for [j, j+8), masked (masked adds contribute exact 0.0f)
#pragma unroll
            for (int u = 0; u < 8; u++) {
                const unsigned m = (j + u < end) ? 0xffffffffu : 0u;
                a0 += bf2f_lo(wa[u].x & m); a1 += bf2f_hi(wa[u].x & m);
                a2 += bf2f_lo(wa[u].y & m); a3 += bf2f_hi(wa[u].y & m);
            }
            j += 8;
            if (!haveB) break;
            // prefetch batch after wb into wa (issues before wb's accumulate)
            const bool haveN = (j + 8 < end);
            if (haveN) {
#pragma unroll
                for (int u = 0; u < 8; u++) r[u] = srcs[min(j + 8 + u, last)];
#pragma unroll
                for (int u = 0; u < 8; u++) wa[u] = LOADG(r[u]);
            }
            // accumulate wb for [j, j+8)
#pragma unroll
            for (int u = 0; u < 8; u++) {
                const unsigned m = (j + u < end) ? 0xffffffffu : 0u;
                a0 += bf2f_lo(wb[u].x & m); a1 += bf2f_hi(wb[u].x & m);
                a2 += bf2f_lo(wb[u].y & m); a3 += bf2f_hi(wb[u].y & m);
            }
            j += 8;
            if (!haveN) break;
            haveB = (j + 8 < end);
            if (haveB) {
#pragma unroll
                for (int u = 0; u < 8; u++) r[u] = srcs[min(j + 8 + u, last)];
#pragma unroll
                for (int u = 0; u < 8; u++) wb[u] = LOADG(r[u]);
            }
        }
    }
#undef LOADG

    const float dv = dinv[c];
    const float4 bc4 = *(const float4*)(bconv + (d4 << 2));
    float v0 = fmaxf(a0 * dv + bc4.x, 0.f);
    float v1 = fmaxf(a1 * dv + bc4.y, 0.f);
    float v2 = fmaxf(a2 * dv + bc4.z, 0.f);
    float v3 = fmaxf(a3 * dv + bc4.w, 0.f);

    // dropout: per-element threefry mapping i = c*64 + d
    const unsigned ib = (unsigned)(c * HID + (d4 << 2));
    unsigned o0, o1;
    threefry2x32_k42(0u, ib + 0u, o0, o1);
    v0 = ((o0 ^ o1) & 0x80000000u) ? 0.f : v0 * 2.f;
    threefry2x32_k42(0u, ib + 1u, o0, o1);
    v1 = ((o0 ^ o1) & 0x80000000u) ? 0.f : v1 * 2.f;
    threefry2x32_k42(0u, ib + 2u, o0, o1);
    v2 = ((o0 ^ o1) & 0x80000000u) ? 0.f : v2 * 2.f;
    threefry2x32_k42(0u, ib + 3u, o0, o1);
    v3 = ((o0 ^ o1) & 0x80000000u) ? 0.f : v3 * 2.f;

    // [64 -> 2] matvec partials: Wlin row-major [64][2]; lane covers rows 4*d4..4*d4+3
    const float4 wl0 = *(const float4*)(Wlin + (d4 << 3));      // rows 4d4, 4d4+1
    const float4 wl1 = *(const float4*)(Wlin + (d4 << 3) + 4);  // rows 4d4+2, 4d4+3
    float p0 = v0 * wl0.x + v1 * wl0.z + v2 * wl1.x + v3 * wl1.z;
    float p1 = v0 * wl0.y + v1 * wl0.w + v2 * wl1.y + v3 * wl1.w;

    // reduce across the 16 lanes of this dst group (aligned, so xor stays in-group)
#pragma unroll
    for (int off = 8; off; off >>= 1) {
        p0 += __shfl_xor(p0, off);
        p1 += __shfl_xor(p1, off);
    }
    if (d4 == 0) {
        *(float2*)(out + (size_t)c * 2) = make_float2(p0 + blin[0], p1 + blin[1]);
    }
}

extern "C" void kernel_launch(void* const* d_in, const int* in_sizes, int n_in,
                              void* d_out, int out_size, void* d_ws, size_t ws_size,
                              hipStream_t stream) {
    // Map inputs BY ELEMENT COUNT (all unique) — robust to positional order.
    const float* x  = (const float*)d_in[0];
    const void*  ei = d_in[1];
    const float* Wc = (const float*)d_in[2];
    const float* bc = (const float*)d_in[3];
    const float* Wl = (const float*)d_in[4];
    const float* bl = (const float*)d_in[5];
    for (int i = 0; i < n_in; i++) {
        switch (in_sizes[i]) {
            case N_NODES * IN_DIM:   x  = (const float*)d_in[i]; break;
            case 2 * N_EDGES:
            case 4 * N_EDGES:        ei = d_in[i]; break;
            case IN_DIM * HID:       Wc = (const float*)d_in[i]; break;
            case HID:                bc = (const float*)d_in[i]; break;
            case HID * 2:            Wl = (const float*)d_in[i]; break;
            case 2:                  bl = (const float*)d_in[i]; break;
            default: break;
        }
    }
    float* out = (float*)d_out;

    const int* src = (const int*)ei;            // edge_index[0] (int32, proven r2≡r3)
    const int* dst = (const int*)ei + N_EDGES;  // edge_index[1]

    char* ws = (char*)d_ws;
    size_t off = 0;
    unsigned short* gm = (unsigned short*)(ws + off); off += (size_t)N_NODES * HID * 2;  // 12.8 MB
    float* dinv        = (float*)(ws + off);   off += (size_t)N_NODES * 4;               // 0.4 MB
    int2*  row_se      = (int2*)(ws + off);    off += (size_t)N_NODES * 8;               // 0.8 MB
    int*   bucketcnt   = (int*)(ws + off);     off += (size_t)(NB + 64) * 4;
    off = (off + 255) & ~(size_t)255;
    unsigned* gbuf     = (unsigned*)(ws + off); off += (size_t)NB * MAXPB * 4;           // 12.8 MB
    // gbuf doubles as srcs (records overwritten in place by k_csr3)

    hipMemsetAsync(bucketcnt, 0, (size_t)NB * 4, stream);
    k_bucket<<<BUCKET_BLOCKS, 512, 0, stream>>>(src, dst, bucketcnt, gbuf);
    k_csr3<<<NB, 256, 0, stream>>>(gbuf, bucketcnt, row_se, dinv);
    k_gemm<<<(N_NODES + 63) / 64, 256, 0, stream>>>(x, Wc, dinv, gm);
    k_aggr<<<(N_NODES + 15) / 16, 256, 0, stream>>>(gm, row_se, (const int*)gbuf,
                                                    dinv, bc, Wl, bl, out);
}